// Round 1
// baseline (609.819 us; speedup 1.0000x reference)
//
#include <hip/hip_runtime.h>

// GCN, N=50000 nodes, E=800000 edges, 128->128(relu)->64, fp32 throughout.
// Strategy: build CSR of incoming edges once per call (count/scan/fill),
// then each layer = dense GEMM (wave-per-node, W rows L1/L2-cached) +
// gather-aggregate (wave-per-node over incoming edge list, no fp atomics).

#define Nn 50000
#define Ne 800000

// ---------------- degree count ----------------
__global__ __launch_bounds__(256) void k_count(const int* __restrict__ col,
                                               int* __restrict__ degi) {
  int e = blockIdx.x * 256 + threadIdx.x;
  if (e < Ne) atomicAdd(&degi[col[e]], 1);
}

// ---------------- exclusive scan of degrees + dis = rsqrt(deg+1) ----------------
__global__ __launch_bounds__(1024) void k_scan(const int* __restrict__ degi,
                                               int* __restrict__ rowptr,
                                               float* __restrict__ dis) {
  __shared__ int wsum[16];
  __shared__ int carry_s;
  int tid = threadIdx.x;
  int lane = tid & 63, wid = tid >> 6;
  if (tid == 0) carry_s = 0;
  __syncthreads();
  for (int base = 0; base < Nn; base += 1024) {
    int i = base + tid;
    int v = (i < Nn) ? degi[i] : 0;
    if (i < Nn) dis[i] = rsqrtf((float)(v + 1));   // self-loop adds 1
    int incl = v;
    #pragma unroll
    for (int off = 1; off < 64; off <<= 1) {
      int t = __shfl_up(incl, off);
      if (lane >= off) incl += t;
    }
    if (lane == 63) wsum[wid] = incl;
    __syncthreads();
    if (wid == 0) {
      int wv = (lane < 16) ? wsum[lane] : 0;
      #pragma unroll
      for (int off = 1; off < 16; off <<= 1) {
        int t = __shfl_up(wv, off);
        if (lane >= off) wv += t;
      }
      if (lane < 16) wsum[lane] = wv;  // inclusive over wave totals
    }
    __syncthreads();
    int woff = (wid > 0) ? wsum[wid - 1] : 0;
    int carry = carry_s;
    if (i < Nn) rowptr[i] = carry + woff + incl - v;  // exclusive
    __syncthreads();
    if (tid == 1023) carry_s = carry + wsum[15];
    __syncthreads();
  }
  if (tid == 0) rowptr[Nn] = carry_s;  // == Ne
}

// ---------------- CSR fill (incoming lists) ----------------
__global__ __launch_bounds__(256) void k_fill(const int* __restrict__ row,
                                              const int* __restrict__ col,
                                              const float* __restrict__ dis,
                                              const int* __restrict__ rowptr,
                                              int* __restrict__ cursor,
                                              int* __restrict__ csr_src,
                                              float* __restrict__ csr_norm) {
  int e = blockIdx.x * 256 + threadIdx.x;
  if (e >= Ne) return;
  int r = row[e], c = col[e];
  int pos = rowptr[c] + atomicAdd(&cursor[c], 1);
  csr_src[pos] = r;
  csr_norm[pos] = dis[r] * dis[c];
}

// ---------------- GEMM: H[n,128] = X[n,128] @ W[128,128] ----------------
__global__ __launch_bounds__(256) void k_gemm128(const float* __restrict__ X,
                                                 const float* __restrict__ W,
                                                 float* __restrict__ H, int n) {
  __shared__ float xs[4][128];
  int wid = threadIdx.x >> 6, lane = threadIdx.x & 63;
  int node = blockIdx.x * 4 + wid;
  int nc = node < n ? node : n - 1;
  const float* xr = X + (size_t)nc * 128;
  xs[wid][lane] = xr[lane];
  xs[wid][lane + 64] = xr[lane + 64];
  __syncthreads();
  if (node >= n) return;
  float a0 = 0.f, a1 = 0.f;
  #pragma unroll 4
  for (int k = 0; k < 128; ++k) {
    float xk = xs[wid][k];                       // LDS broadcast (free)
    float2 w = *(const float2*)(W + k * 128 + 2 * lane);  // coalesced 512B/wave
    a0 = fmaf(xk, w.x, a0);
    a1 = fmaf(xk, w.y, a1);
  }
  *(float2*)(H + (size_t)node * 128 + 2 * lane) = make_float2(a0, a1);
}

// ---------------- GEMM: H[n,64] = X[n,128] @ W[128,64] ----------------
__global__ __launch_bounds__(256) void k_gemm64(const float* __restrict__ X,
                                                const float* __restrict__ W,
                                                float* __restrict__ H, int n) {
  __shared__ float xs[4][128];
  int wid = threadIdx.x >> 6, lane = threadIdx.x & 63;
  int node = blockIdx.x * 4 + wid;
  int nc = node < n ? node : n - 1;
  const float* xr = X + (size_t)nc * 128;
  xs[wid][lane] = xr[lane];
  xs[wid][lane + 64] = xr[lane + 64];
  __syncthreads();
  if (node >= n) return;
  float a0 = 0.f;
  #pragma unroll 4
  for (int k = 0; k < 128; ++k) {
    a0 = fmaf(xs[wid][k], W[k * 64 + lane], a0);
  }
  H[(size_t)node * 64 + lane] = a0;
}

// ---------------- aggregate 128 feats (+bias, relu) ----------------
__global__ __launch_bounds__(256) void k_agg128(const float* __restrict__ H,
                                                const int* __restrict__ csr_src,
                                                const float* __restrict__ csr_norm,
                                                const int* __restrict__ rowptr,
                                                const float* __restrict__ dis,
                                                const float* __restrict__ bias,
                                                float* __restrict__ Out, int n) {
  int wid = threadIdx.x >> 6, lane = threadIdx.x & 63;
  int v = blockIdx.x * 4 + wid;
  if (v >= n) return;
  int s = rowptr[v], e = rowptr[v + 1];
  float d = dis[v];
  float sw = d * d;                              // self-loop norm = 1/deg
  float2 h = *(const float2*)(H + (size_t)v * 128 + 2 * lane);
  float a0 = h.x * sw, a1 = h.y * sw;
  for (int i = s; i < e; ++i) {
    int src = csr_src[i];                        // wave-uniform -> s_load
    float w = csr_norm[i];
    float2 hs = *(const float2*)(H + (size_t)src * 128 + 2 * lane);
    a0 = fmaf(w, hs.x, a0);
    a1 = fmaf(w, hs.y, a1);
  }
  float2 b = *(const float2*)(bias + 2 * lane);
  a0 = fmaxf(a0 + b.x, 0.f);
  a1 = fmaxf(a1 + b.y, 0.f);
  *(float2*)(Out + (size_t)v * 128 + 2 * lane) = make_float2(a0, a1);
}

// ---------------- aggregate 64 feats (+bias, no relu) ----------------
__global__ __launch_bounds__(256) void k_agg64(const float* __restrict__ H,
                                               const int* __restrict__ csr_src,
                                               const float* __restrict__ csr_norm,
                                               const int* __restrict__ rowptr,
                                               const float* __restrict__ dis,
                                               const float* __restrict__ bias,
                                               float* __restrict__ Out, int n) {
  int wid = threadIdx.x >> 6, lane = threadIdx.x & 63;
  int v = blockIdx.x * 4 + wid;
  if (v >= n) return;
  int s = rowptr[v], e = rowptr[v + 1];
  float d = dis[v];
  float a0 = H[(size_t)v * 64 + lane] * (d * d);
  for (int i = s; i < e; ++i) {
    int src = csr_src[i];
    float w = csr_norm[i];
    a0 = fmaf(w, H[(size_t)src * 64 + lane], a0);
  }
  Out[(size_t)v * 64 + lane] = a0 + bias[lane];
}

extern "C" void kernel_launch(void* const* d_in, const int* in_sizes, int n_in,
                              void* d_out, int out_size, void* d_ws, size_t ws_size,
                              hipStream_t stream) {
  const float* x  = (const float*)d_in[0];
  const int*   ei = (const int*)d_in[1];    // [2, E] row-major
  const int*   row = ei;                    // edge_index[0] (source)
  const int*   col = ei + Ne;               // edge_index[1] (dest / segment)
  const float* W1 = (const float*)d_in[2];
  const float* b1 = (const float*)d_in[3];
  const float* W2 = (const float*)d_in[4];
  const float* b2 = (const float*)d_in[5];
  float* out = (float*)d_out;

  char* ws = (char*)d_ws;
  size_t off = 0;
  auto alloc = [&](size_t bytes) -> void* {
    void* p = ws + off;
    off += (bytes + 255) & ~(size_t)255;
    return p;
  };
  int*   degi     = (int*)  alloc(Nn * sizeof(int));
  int*   cursor   = (int*)  alloc(Nn * sizeof(int));
  int*   rowptr   = (int*)  alloc((Nn + 1) * sizeof(int));
  float* dis      = (float*)alloc(Nn * sizeof(float));
  int*   csr_src  = (int*)  alloc(Ne * sizeof(int));
  float* csr_norm = (float*)alloc(Ne * sizeof(float));
  float* H1       = (float*)alloc((size_t)Nn * 128 * sizeof(float));
  float* H1b      = (float*)alloc((size_t)Nn * 128 * sizeof(float));
  float* H2       = (float*)alloc((size_t)Nn * 64 * sizeof(float));
  // total ~71 MB

  hipMemsetAsync(degi, 0, Nn * sizeof(int), stream);
  hipMemsetAsync(cursor, 0, Nn * sizeof(int), stream);

  const int EB = (Ne + 255) / 256;          // 3125
  const int NB = (Nn + 3) / 4;              // 12500 (wave per node)

  k_count<<<EB, 256, 0, stream>>>(col, degi);
  k_scan<<<1, 1024, 0, stream>>>(degi, rowptr, dis);
  k_fill<<<EB, 256, 0, stream>>>(row, col, dis, rowptr, cursor, csr_src, csr_norm);

  // layer 1: H1 = x @ W1 ; H1b = relu(agg(H1) + b1)
  k_gemm128<<<NB, 256, 0, stream>>>(x, W1, H1, Nn);
  k_agg128<<<NB, 256, 0, stream>>>(H1, csr_src, csr_norm, rowptr, dis, b1, H1b, Nn);

  // layer 2: H2 = H1b @ W2 ; out = agg(H2) + b2
  k_gemm64<<<NB, 256, 0, stream>>>(H1b, W2, H2, Nn);
  k_agg64<<<NB, 256, 0, stream>>>(H2, csr_src, csr_norm, rowptr, dis, b2, out, Nn);
}

// Round 2
// 422.183 us; speedup vs baseline: 1.4444x; 1.4444x over previous
//
#include <hip/hip_runtime.h>

// GCN, N=50000 nodes, E=800000 edges, 128->128(relu)->64, fp32 throughout.
// CSR build (count/scan/fill) -> per layer: LDS-tiled fp32 GEMM + gather-agg.

#define Nn 50000
#define Ne 800000

// ---------------- degree count ----------------
__global__ __launch_bounds__(256) void k_count(const int* __restrict__ col,
                                               int* __restrict__ degi) {
  int e = blockIdx.x * 256 + threadIdx.x;
  if (e < Ne) atomicAdd(&degi[col[e]], 1);
}

// ---------------- exclusive scan of degrees + dis = rsqrt(deg+1) ----------------
__global__ __launch_bounds__(1024) void k_scan(const int* __restrict__ degi,
                                               int* __restrict__ rowptr,
                                               float* __restrict__ dis) {
  __shared__ int wsum[16];
  __shared__ int carry_s;
  int tid = threadIdx.x;
  int lane = tid & 63, wid = tid >> 6;
  if (tid == 0) carry_s = 0;
  __syncthreads();
  for (int base = 0; base < Nn; base += 1024) {
    int i = base + tid;
    int v = (i < Nn) ? degi[i] : 0;
    if (i < Nn) dis[i] = rsqrtf((float)(v + 1));   // self-loop adds 1
    int incl = v;
    #pragma unroll
    for (int off = 1; off < 64; off <<= 1) {
      int t = __shfl_up(incl, off);
      if (lane >= off) incl += t;
    }
    if (lane == 63) wsum[wid] = incl;
    __syncthreads();
    if (wid == 0) {
      int wv = (lane < 16) ? wsum[lane] : 0;
      #pragma unroll
      for (int off = 1; off < 16; off <<= 1) {
        int t = __shfl_up(wv, off);
        if (lane >= off) wv += t;
      }
      if (lane < 16) wsum[lane] = wv;  // inclusive over wave totals
    }
    __syncthreads();
    int woff = (wid > 0) ? wsum[wid - 1] : 0;
    int carry = carry_s;
    if (i < Nn) rowptr[i] = carry + woff + incl - v;  // exclusive
    __syncthreads();
    if (tid == 1023) carry_s = carry + wsum[15];
    __syncthreads();
  }
  if (tid == 0) rowptr[Nn] = carry_s;  // == Ne
}

// ---------------- CSR fill (incoming lists) ----------------
__global__ __launch_bounds__(256) void k_fill(const int* __restrict__ row,
                                              const int* __restrict__ col,
                                              const float* __restrict__ dis,
                                              const int* __restrict__ rowptr,
                                              int* __restrict__ cursor,
                                              int* __restrict__ csr_src,
                                              float* __restrict__ csr_norm) {
  int e = blockIdx.x * 256 + threadIdx.x;
  if (e >= Ne) return;
  int r = row[e], c = col[e];
  int pos = rowptr[c] + atomicAdd(&cursor[c], 1);
  csr_src[pos] = r;
  csr_norm[pos] = dis[r] * dis[c];
}

// ---------------- tiled GEMM: H[n, ldo] = X[n,128] @ W[128, ldo] ----------------
// Block: 256 thr = 16 tx (4 cols each) x 16 ty (4 nodes each).
// LDS: W col-slice 128x64 (32 KB) + X tile 64x128 (32 KB) = 64 KB -> 2 blocks/CU.
// grid.x = node tiles (64 nodes each), grid.y = ldo/64 col slices.
__global__ __launch_bounds__(256) void k_gemm(const float* __restrict__ X,
                                              const float* __restrict__ W,
                                              float* __restrict__ H,
                                              int n, int ldo) {
  __shared__ float Wl[128 * 64];   // [k][c] c within slice
  __shared__ float Xl[64 * 128];   // [node][k]
  const int tid = threadIdx.x;
  const int tx = tid & 15, ty = tid >> 4;
  const int base = blockIdx.x * 64;
  const int colbase = blockIdx.y * 64;

  // stage W slice: 2048 float4, 8 per thread, coalesced
  {
    const float4* Wg = (const float4*)W;
    float4* Ws = (float4*)Wl;
    const int ldw4 = ldo >> 2, cb4 = colbase >> 2;
    #pragma unroll
    for (int i = 0; i < 8; ++i) {
      int idx = tid + i * 256;          // 0..2047
      int r = idx >> 4, c4 = idx & 15;
      Ws[idx] = Wg[r * ldw4 + cb4 + c4];
    }
  }
  // stage X tile: 2048 float4, 8 per thread, coalesced
  {
    const float4* Xg = (const float4*)X;
    float4* Xs = (float4*)Xl;
    #pragma unroll
    for (int i = 0; i < 8; ++i) {
      int idx = tid + i * 256;          // 0..2047
      int node = base + (idx >> 5);
      int nc = node < n ? node : n - 1;
      Xs[idx] = Xg[(size_t)nc * 32 + (idx & 31)];
    }
  }
  __syncthreads();

  float a[4][4];
  #pragma unroll
  for (int m = 0; m < 4; ++m)
    #pragma unroll
    for (int c = 0; c < 4; ++c) a[m][c] = 0.f;

  #pragma unroll 4
  for (int k = 0; k < 128; k += 4) {
    float4 w0 = *(const float4*)&Wl[(k + 0) * 64 + (tx << 2)];
    float4 w1 = *(const float4*)&Wl[(k + 1) * 64 + (tx << 2)];
    float4 w2 = *(const float4*)&Wl[(k + 2) * 64 + (tx << 2)];
    float4 w3 = *(const float4*)&Wl[(k + 3) * 64 + (tx << 2)];
    #pragma unroll
    for (int m = 0; m < 4; ++m) {
      float4 xv = *(const float4*)&Xl[(ty * 4 + m) * 128 + k];
      a[m][0] = fmaf(xv.x, w0.x, a[m][0]);
      a[m][0] = fmaf(xv.y, w1.x, a[m][0]);
      a[m][0] = fmaf(xv.z, w2.x, a[m][0]);
      a[m][0] = fmaf(xv.w, w3.x, a[m][0]);
      a[m][1] = fmaf(xv.x, w0.y, a[m][1]);
      a[m][1] = fmaf(xv.y, w1.y, a[m][1]);
      a[m][1] = fmaf(xv.z, w2.y, a[m][1]);
      a[m][1] = fmaf(xv.w, w3.y, a[m][1]);
      a[m][2] = fmaf(xv.x, w0.z, a[m][2]);
      a[m][2] = fmaf(xv.y, w1.z, a[m][2]);
      a[m][2] = fmaf(xv.z, w2.z, a[m][2]);
      a[m][2] = fmaf(xv.w, w3.z, a[m][2]);
      a[m][3] = fmaf(xv.x, w0.w, a[m][3]);
      a[m][3] = fmaf(xv.y, w1.w, a[m][3]);
      a[m][3] = fmaf(xv.z, w2.w, a[m][3]);
      a[m][3] = fmaf(xv.w, w3.w, a[m][3]);
    }
  }

  #pragma unroll
  for (int m = 0; m < 4; ++m) {
    int node = base + ty * 4 + m;
    if (node < n) {
      float4 o = make_float4(a[m][0], a[m][1], a[m][2], a[m][3]);
      *(float4*)(H + (size_t)node * ldo + colbase + (tx << 2)) = o;
    }
  }
}

// ---------------- aggregate 128 feats (+bias, relu) ----------------
__global__ __launch_bounds__(256) void k_agg128(const float* __restrict__ H,
                                                const int* __restrict__ csr_src,
                                                const float* __restrict__ csr_norm,
                                                const int* __restrict__ rowptr,
                                                const float* __restrict__ dis,
                                                const float* __restrict__ bias,
                                                float* __restrict__ Out, int n) {
  int wid = threadIdx.x >> 6, lane = threadIdx.x & 63;
  int v = blockIdx.x * 4 + wid;
  if (v >= n) return;
  int s = rowptr[v], e = rowptr[v + 1];
  float d = dis[v];
  float sw = d * d;                              // self-loop norm = 1/deg
  float2 h = *(const float2*)(H + (size_t)v * 128 + 2 * lane);
  float a0 = h.x * sw, a1 = h.y * sw;
  for (int i = s; i < e; ++i) {
    int src = csr_src[i];                        // wave-uniform -> s_load
    float w = csr_norm[i];
    float2 hs = *(const float2*)(H + (size_t)src * 128 + 2 * lane);
    a0 = fmaf(w, hs.x, a0);
    a1 = fmaf(w, hs.y, a1);
  }
  float2 b = *(const float2*)(bias + 2 * lane);
  a0 = fmaxf(a0 + b.x, 0.f);
  a1 = fmaxf(a1 + b.y, 0.f);
  *(float2*)(Out + (size_t)v * 128 + 2 * lane) = make_float2(a0, a1);
}

// ---------------- aggregate 64 feats (+bias, no relu) ----------------
__global__ __launch_bounds__(256) void k_agg64(const float* __restrict__ H,
                                               const int* __restrict__ csr_src,
                                               const float* __restrict__ csr_norm,
                                               const int* __restrict__ rowptr,
                                               const float* __restrict__ dis,
                                               const float* __restrict__ bias,
                                               float* __restrict__ Out, int n) {
  int wid = threadIdx.x >> 6, lane = threadIdx.x & 63;
  int v = blockIdx.x * 4 + wid;
  if (v >= n) return;
  int s = rowptr[v], e = rowptr[v + 1];
  float d = dis[v];
  float a0 = H[(size_t)v * 64 + lane] * (d * d);
  for (int i = s; i < e; ++i) {
    int src = csr_src[i];
    float w = csr_norm[i];
    a0 = fmaf(w, H[(size_t)src * 64 + lane], a0);
  }
  Out[(size_t)v * 64 + lane] = a0 + bias[lane];
}

extern "C" void kernel_launch(void* const* d_in, const int* in_sizes, int n_in,
                              void* d_out, int out_size, void* d_ws, size_t ws_size,
                              hipStream_t stream) {
  const float* x  = (const float*)d_in[0];
  const int*   ei = (const int*)d_in[1];    // [2, E] row-major
  const int*   row = ei;                    // edge_index[0] (source)
  const int*   col = ei + Ne;               // edge_index[1] (dest / segment)
  const float* W1 = (const float*)d_in[2];
  const float* b1 = (const float*)d_in[3];
  const float* W2 = (const float*)d_in[4];
  const float* b2 = (const float*)d_in[5];
  float* out = (float*)d_out;

  char* ws = (char*)d_ws;
  size_t off = 0;
  auto alloc = [&](size_t bytes) -> void* {
    void* p = ws + off;
    off += (bytes + 255) & ~(size_t)255;
    return p;
  };
  int*   degi     = (int*)  alloc(Nn * sizeof(int));
  int*   cursor   = (int*)  alloc(Nn * sizeof(int));
  int*   rowptr   = (int*)  alloc((Nn + 1) * sizeof(int));
  float* dis      = (float*)alloc(Nn * sizeof(float));
  int*   csr_src  = (int*)  alloc(Ne * sizeof(int));
  float* csr_norm = (float*)alloc(Ne * sizeof(float));
  float* H1       = (float*)alloc((size_t)Nn * 128 * sizeof(float));
  float* H1b      = (float*)alloc((size_t)Nn * 128 * sizeof(float));
  float* H2       = (float*)alloc((size_t)Nn * 64 * sizeof(float));
  // total ~71 MB

  hipMemsetAsync(degi, 0, Nn * sizeof(int), stream);
  hipMemsetAsync(cursor, 0, Nn * sizeof(int), stream);

  const int EB = (Ne + 255) / 256;          // 3125
  const int NB = (Nn + 3) / 4;              // 12500 (wave per node, agg)
  const int GT = (Nn + 63) / 64;            // 782 node tiles (gemm)

  k_count<<<EB, 256, 0, stream>>>(col, degi);
  k_scan<<<1, 1024, 0, stream>>>(degi, rowptr, dis);
  k_fill<<<EB, 256, 0, stream>>>(row, col, dis, rowptr, cursor, csr_src, csr_norm);

  // layer 1: H1 = x @ W1 ; H1b = relu(agg(H1) + b1)
  k_gemm<<<dim3(GT, 2), 256, 0, stream>>>(x, W1, H1, Nn, 128);
  k_agg128<<<NB, 256, 0, stream>>>(H1, csr_src, csr_norm, rowptr, dis, b1, H1b, Nn);

  // layer 2: H2 = H1b @ W2 ; out = agg(H2) + b2
  k_gemm<<<dim3(GT, 1), 256, 0, stream>>>(H1b, W2, H2, Nn, 64);
  k_agg64<<<NB, 256, 0, stream>>>(H2, csr_src, csr_norm, rowptr, dis, b2, out, Nn);
}

// Round 3
// 311.306 us; speedup vs baseline: 1.9589x; 1.3562x over previous
//
#include <hip/hip_runtime.h>

// GCN, N=50000 nodes, E=800000 edges, 128->128(relu)->64, fp32 throughout.
// CSR build (count / 3-phase parallel scan / fill) -> per layer:
// LDS-tiled fp32 GEMM + gather-aggregate with 8-wide edge batching (MLP).

#define Nn 50000
#define Ne 800000
#define SCAN_B ((Nn + 1023) / 1024)   // 49 blocks

// ---------------- degree count ----------------
__global__ __launch_bounds__(256) void k_count(const int* __restrict__ col,
                                               int* __restrict__ degi) {
  int e = blockIdx.x * 256 + threadIdx.x;
  if (e < Ne) atomicAdd(&degi[col[e]], 1);
}

// ---------------- scan phase 1: block-local exclusive scan + dis ----------------
__global__ __launch_bounds__(1024) void k_scan1(const int* __restrict__ degi,
                                                int* __restrict__ rowptr,
                                                float* __restrict__ dis,
                                                int* __restrict__ bsum) {
  __shared__ int wsum[16];
  int tid = threadIdx.x;
  int lane = tid & 63, wid = tid >> 6;
  int i = blockIdx.x * 1024 + tid;
  int v = (i < Nn) ? degi[i] : 0;
  if (i < Nn) dis[i] = rsqrtf((float)(v + 1));   // self-loop adds 1
  int incl = v;
  #pragma unroll
  for (int off = 1; off < 64; off <<= 1) {
    int t = __shfl_up(incl, off);
    if (lane >= off) incl += t;
  }
  if (lane == 63) wsum[wid] = incl;
  __syncthreads();
  if (wid == 0) {
    int wv = (lane < 16) ? wsum[lane] : 0;
    #pragma unroll
    for (int off = 1; off < 16; off <<= 1) {
      int t = __shfl_up(wv, off);
      if (lane >= off) wv += t;
    }
    if (lane < 16) wsum[lane] = wv;  // inclusive over wave totals
  }
  __syncthreads();
  int woff = (wid > 0) ? wsum[wid - 1] : 0;
  if (i < Nn) rowptr[i] = woff + incl - v;       // block-local exclusive
  if (tid == 0) bsum[blockIdx.x] = wsum[15];     // block total
}

// ---------------- scan phase 2: exclusive scan of 49 block sums ----------------
__global__ __launch_bounds__(64) void k_scan2(int* __restrict__ bsum,
                                              int* __restrict__ rowptr) {
  int lane = threadIdx.x;
  int v = (lane < SCAN_B) ? bsum[lane] : 0;
  int incl = v;
  #pragma unroll
  for (int off = 1; off < 64; off <<= 1) {
    int t = __shfl_up(incl, off);
    if (lane >= off) incl += t;
  }
  if (lane < SCAN_B) bsum[lane] = incl - v;      // exclusive block offsets
  if (lane == 63) rowptr[Nn] = incl;             // == Ne
}

// ---------------- scan phase 3: add block offsets ----------------
__global__ __launch_bounds__(1024) void k_scan3(int* __restrict__ rowptr,
                                                const int* __restrict__ bsum) {
  int i = blockIdx.x * 1024 + threadIdx.x;
  if (i < Nn) rowptr[i] += bsum[blockIdx.x];
}

// ---------------- CSR fill (incoming lists) ----------------
__global__ __launch_bounds__(256) void k_fill(const int* __restrict__ row,
                                              const int* __restrict__ col,
                                              const float* __restrict__ dis,
                                              const int* __restrict__ rowptr,
                                              int* __restrict__ cursor,
                                              int* __restrict__ csr_src,
                                              float* __restrict__ csr_norm) {
  int e = blockIdx.x * 256 + threadIdx.x;
  if (e >= Ne) return;
  int r = row[e], c = col[e];
  int pos = rowptr[c] + atomicAdd(&cursor[c], 1);
  csr_src[pos] = r;
  csr_norm[pos] = dis[r] * dis[c];
}

// ---------------- tiled GEMM: H[n, ldo] = X[n,128] @ W[128, ldo] ----------------
// Block: 256 thr = 16 tx (4 cols each) x 16 ty (4 nodes each).
// LDS: W col-slice 128x64 (32 KB) + X tile 64x128 (32 KB) = 64 KB -> 2 blocks/CU.
__global__ __launch_bounds__(256) void k_gemm(const float* __restrict__ X,
                                              const float* __restrict__ W,
                                              float* __restrict__ H,
                                              int n, int ldo) {
  __shared__ float Wl[128 * 64];   // [k][c] c within slice
  __shared__ float Xl[64 * 128];   // [node][k]
  const int tid = threadIdx.x;
  const int tx = tid & 15, ty = tid >> 4;
  const int base = blockIdx.x * 64;
  const int colbase = blockIdx.y * 64;

  {
    const float4* Wg = (const float4*)W;
    float4* Ws = (float4*)Wl;
    const int ldw4 = ldo >> 2, cb4 = colbase >> 2;
    #pragma unroll
    for (int i = 0; i < 8; ++i) {
      int idx = tid + i * 256;          // 0..2047
      int r = idx >> 4, c4 = idx & 15;
      Ws[idx] = Wg[r * ldw4 + cb4 + c4];
    }
  }
  {
    const float4* Xg = (const float4*)X;
    float4* Xs = (float4*)Xl;
    #pragma unroll
    for (int i = 0; i < 8; ++i) {
      int idx = tid + i * 256;          // 0..2047
      int node = base + (idx >> 5);
      int nc = node < n ? node : n - 1;
      Xs[idx] = Xg[(size_t)nc * 32 + (idx & 31)];
    }
  }
  __syncthreads();

  float a[4][4];
  #pragma unroll
  for (int m = 0; m < 4; ++m)
    #pragma unroll
    for (int c = 0; c < 4; ++c) a[m][c] = 0.f;

  #pragma unroll 4
  for (int k = 0; k < 128; k += 4) {
    float4 w0 = *(const float4*)&Wl[(k + 0) * 64 + (tx << 2)];
    float4 w1 = *(const float4*)&Wl[(k + 1) * 64 + (tx << 2)];
    float4 w2 = *(const float4*)&Wl[(k + 2) * 64 + (tx << 2)];
    float4 w3 = *(const float4*)&Wl[(k + 3) * 64 + (tx << 2)];
    #pragma unroll
    for (int m = 0; m < 4; ++m) {
      float4 xv = *(const float4*)&Xl[(ty * 4 + m) * 128 + k];
      a[m][0] = fmaf(xv.x, w0.x, a[m][0]);
      a[m][0] = fmaf(xv.y, w1.x, a[m][0]);
      a[m][0] = fmaf(xv.z, w2.x, a[m][0]);
      a[m][0] = fmaf(xv.w, w3.x, a[m][0]);
      a[m][1] = fmaf(xv.x, w0.y, a[m][1]);
      a[m][1] = fmaf(xv.y, w1.y, a[m][1]);
      a[m][1] = fmaf(xv.z, w2.y, a[m][1]);
      a[m][1] = fmaf(xv.w, w3.y, a[m][1]);
      a[m][2] = fmaf(xv.x, w0.z, a[m][2]);
      a[m][2] = fmaf(xv.y, w1.z, a[m][2]);
      a[m][2] = fmaf(xv.z, w2.z, a[m][2]);
      a[m][2] = fmaf(xv.w, w3.z, a[m][2]);
      a[m][3] = fmaf(xv.x, w0.w, a[m][3]);
      a[m][3] = fmaf(xv.y, w1.w, a[m][3]);
      a[m][3] = fmaf(xv.z, w2.w, a[m][3]);
      a[m][3] = fmaf(xv.w, w3.w, a[m][3]);
    }
  }

  #pragma unroll
  for (int m = 0; m < 4; ++m) {
    int node = base + ty * 4 + m;
    if (node < n) {
      float4 o = make_float4(a[m][0], a[m][1], a[m][2], a[m][3]);
      *(float4*)(H + (size_t)node * ldo + colbase + (tx << 2)) = o;
    }
  }
}

// ---------------- aggregate 128 feats (+bias, relu), 8-wide edge batch ----------------
__global__ __launch_bounds__(256) void k_agg128(const float* __restrict__ H,
                                                const int* __restrict__ csr_src,
                                                const float* __restrict__ csr_norm,
                                                const int* __restrict__ rowptr,
                                                const float* __restrict__ dis,
                                                const float* __restrict__ bias,
                                                float* __restrict__ Out, int n) {
  int wid = threadIdx.x >> 6, lane = threadIdx.x & 63;
  int v = blockIdx.x * 4 + wid;
  if (v >= n) return;
  int s = rowptr[v], e = rowptr[v + 1];
  float d = dis[v];
  float sw = d * d;                              // self-loop norm = 1/deg
  float2 h = *(const float2*)(H + (size_t)v * 128 + 2 * lane);
  float a0 = h.x * sw, a1 = h.y * sw;
  int i = s;
  for (; i + 8 <= e; i += 8) {
    int   s0 = csr_src[i + 0], s1 = csr_src[i + 1], s2 = csr_src[i + 2], s3 = csr_src[i + 3];
    int   s4 = csr_src[i + 4], s5 = csr_src[i + 5], s6 = csr_src[i + 6], s7 = csr_src[i + 7];
    float w0 = csr_norm[i + 0], w1 = csr_norm[i + 1], w2 = csr_norm[i + 2], w3 = csr_norm[i + 3];
    float w4 = csr_norm[i + 4], w5 = csr_norm[i + 5], w6 = csr_norm[i + 6], w7 = csr_norm[i + 7];
    float2 h0 = *(const float2*)(H + (size_t)s0 * 128 + 2 * lane);
    float2 h1 = *(const float2*)(H + (size_t)s1 * 128 + 2 * lane);
    float2 h2 = *(const float2*)(H + (size_t)s2 * 128 + 2 * lane);
    float2 h3 = *(const float2*)(H + (size_t)s3 * 128 + 2 * lane);
    float2 h4 = *(const float2*)(H + (size_t)s4 * 128 + 2 * lane);
    float2 h5 = *(const float2*)(H + (size_t)s5 * 128 + 2 * lane);
    float2 h6 = *(const float2*)(H + (size_t)s6 * 128 + 2 * lane);
    float2 h7 = *(const float2*)(H + (size_t)s7 * 128 + 2 * lane);
    a0 = fmaf(w0, h0.x, a0); a1 = fmaf(w0, h0.y, a1);
    a0 = fmaf(w1, h1.x, a0); a1 = fmaf(w1, h1.y, a1);
    a0 = fmaf(w2, h2.x, a0); a1 = fmaf(w2, h2.y, a1);
    a0 = fmaf(w3, h3.x, a0); a1 = fmaf(w3, h3.y, a1);
    a0 = fmaf(w4, h4.x, a0); a1 = fmaf(w4, h4.y, a1);
    a0 = fmaf(w5, h5.x, a0); a1 = fmaf(w5, h5.y, a1);
    a0 = fmaf(w6, h6.x, a0); a1 = fmaf(w6, h6.y, a1);
    a0 = fmaf(w7, h7.x, a0); a1 = fmaf(w7, h7.y, a1);
  }
  for (; i < e; ++i) {
    int src = csr_src[i];
    float w = csr_norm[i];
    float2 hs = *(const float2*)(H + (size_t)src * 128 + 2 * lane);
    a0 = fmaf(w, hs.x, a0);
    a1 = fmaf(w, hs.y, a1);
  }
  float2 b = *(const float2*)(bias + 2 * lane);
  a0 = fmaxf(a0 + b.x, 0.f);
  a1 = fmaxf(a1 + b.y, 0.f);
  *(float2*)(Out + (size_t)v * 128 + 2 * lane) = make_float2(a0, a1);
}

// ---------------- aggregate 64 feats (+bias, no relu), 8-wide edge batch ----------------
__global__ __launch_bounds__(256) void k_agg64(const float* __restrict__ H,
                                               const int* __restrict__ csr_src,
                                               const float* __restrict__ csr_norm,
                                               const int* __restrict__ rowptr,
                                               const float* __restrict__ dis,
                                               const float* __restrict__ bias,
                                               float* __restrict__ Out, int n) {
  int wid = threadIdx.x >> 6, lane = threadIdx.x & 63;
  int v = blockIdx.x * 4 + wid;
  if (v >= n) return;
  int s = rowptr[v], e = rowptr[v + 1];
  float d = dis[v];
  float a0 = H[(size_t)v * 64 + lane] * (d * d);
  int i = s;
  for (; i + 8 <= e; i += 8) {
    int   s0 = csr_src[i + 0], s1 = csr_src[i + 1], s2 = csr_src[i + 2], s3 = csr_src[i + 3];
    int   s4 = csr_src[i + 4], s5 = csr_src[i + 5], s6 = csr_src[i + 6], s7 = csr_src[i + 7];
    float w0 = csr_norm[i + 0], w1 = csr_norm[i + 1], w2 = csr_norm[i + 2], w3 = csr_norm[i + 3];
    float w4 = csr_norm[i + 4], w5 = csr_norm[i + 5], w6 = csr_norm[i + 6], w7 = csr_norm[i + 7];
    float h0 = H[(size_t)s0 * 64 + lane];
    float h1 = H[(size_t)s1 * 64 + lane];
    float h2 = H[(size_t)s2 * 64 + lane];
    float h3 = H[(size_t)s3 * 64 + lane];
    float h4 = H[(size_t)s4 * 64 + lane];
    float h5 = H[(size_t)s5 * 64 + lane];
    float h6 = H[(size_t)s6 * 64 + lane];
    float h7 = H[(size_t)s7 * 64 + lane];
    a0 = fmaf(w0, h0, a0); a0 = fmaf(w1, h1, a0);
    a0 = fmaf(w2, h2, a0); a0 = fmaf(w3, h3, a0);
    a0 = fmaf(w4, h4, a0); a0 = fmaf(w5, h5, a0);
    a0 = fmaf(w6, h6, a0); a0 = fmaf(w7, h7, a0);
  }
  for (; i < e; ++i) {
    a0 = fmaf(csr_norm[i], H[(size_t)csr_src[i] * 64 + lane], a0);
  }
  Out[(size_t)v * 64 + lane] = a0 + bias[lane];
}

extern "C" void kernel_launch(void* const* d_in, const int* in_sizes, int n_in,
                              void* d_out, int out_size, void* d_ws, size_t ws_size,
                              hipStream_t stream) {
  const float* x  = (const float*)d_in[0];
  const int*   ei = (const int*)d_in[1];    // [2, E] row-major
  const int*   row = ei;                    // edge_index[0] (source)
  const int*   col = ei + Ne;               // edge_index[1] (dest / segment)
  const float* W1 = (const float*)d_in[2];
  const float* b1 = (const float*)d_in[3];
  const float* W2 = (const float*)d_in[4];
  const float* b2 = (const float*)d_in[5];
  float* out = (float*)d_out;

  char* ws = (char*)d_ws;
  size_t off = 0;
  auto alloc = [&](size_t bytes) -> void* {
    void* p = ws + off;
    off += (bytes + 255) & ~(size_t)255;
    return p;
  };
  int*   degi     = (int*)  alloc(Nn * sizeof(int));
  int*   cursor   = (int*)  alloc(Nn * sizeof(int));
  int*   rowptr   = (int*)  alloc((Nn + 1) * sizeof(int));
  float* dis      = (float*)alloc(Nn * sizeof(float));
  int*   bsum     = (int*)  alloc(64 * sizeof(int));
  int*   csr_src  = (int*)  alloc(Ne * sizeof(int));
  float* csr_norm = (float*)alloc(Ne * sizeof(float));
  float* H1       = (float*)alloc((size_t)Nn * 128 * sizeof(float));
  float* H1b      = (float*)alloc((size_t)Nn * 128 * sizeof(float));
  float* H2       = (float*)alloc((size_t)Nn * 64 * sizeof(float));
  // total ~71 MB

  hipMemsetAsync(degi, 0, Nn * sizeof(int), stream);
  hipMemsetAsync(cursor, 0, Nn * sizeof(int), stream);

  const int EB = (Ne + 255) / 256;          // 3125
  const int NB = (Nn + 3) / 4;              // 12500 (wave per node, agg)
  const int GT = (Nn + 63) / 64;            // 782 node tiles (gemm)

  k_count<<<EB, 256, 0, stream>>>(col, degi);
  k_scan1<<<SCAN_B, 1024, 0, stream>>>(degi, rowptr, dis, bsum);
  k_scan2<<<1, 64, 0, stream>>>(bsum, rowptr);
  k_scan3<<<SCAN_B, 1024, 0, stream>>>(rowptr, bsum);
  k_fill<<<EB, 256, 0, stream>>>(row, col, dis, rowptr, cursor, csr_src, csr_norm);

  // layer 1: H1 = x @ W1 ; H1b = relu(agg(H1) + b1)
  k_gemm<<<dim3(GT, 2), 256, 0, stream>>>(x, W1, H1, Nn, 128);
  k_agg128<<<NB, 256, 0, stream>>>(H1, csr_src, csr_norm, rowptr, dis, b1, H1b, Nn);

  // layer 2: H2 = H1b @ W2 ; out = agg(H2) + b2
  k_gemm<<<dim3(GT, 1), 256, 0, stream>>>(H1b, W2, H2, Nn, 64);
  k_agg64<<<NB, 256, 0, stream>>>(H2, csr_src, csr_norm, rowptr, dis, b2, out, Nn);
}

// Round 4
// 275.408 us; speedup vs baseline: 2.2142x; 1.1303x over previous
//
#include <hip/hip_runtime.h>
#include <hip/hip_fp16.h>

// GCN, N=50000 nodes, E=800000 edges, 128->128(relu)->64, fp32 compute.
// CSR build (count / 3-phase scan / fill, packed int2 edges) -> per layer:
// LDS-tiled fp32 GEMM writing fp16 H + fp16 gather-aggregate (8-wide MLP).
// fp16 H tables halve the per-XCD compulsory L2-miss traffic (random gather
// over a table larger than the 4 MB per-XCD L2 => fetch = 8 x table bytes).

#define Nn 50000
#define Ne 800000
#define SCAN_B ((Nn + 1023) / 1024)   // 49 blocks

// ---------------- degree count ----------------
__global__ __launch_bounds__(256) void k_count(const int* __restrict__ col,
                                               int* __restrict__ degi) {
  int e = blockIdx.x * 256 + threadIdx.x;
  if (e < Ne) atomicAdd(&degi[col[e]], 1);
}

// ---------------- scan phase 1: block-local exclusive scan + dis ----------------
__global__ __launch_bounds__(1024) void k_scan1(const int* __restrict__ degi,
                                                int* __restrict__ rowptr,
                                                float* __restrict__ dis,
                                                int* __restrict__ bsum) {
  __shared__ int wsum[16];
  int tid = threadIdx.x;
  int lane = tid & 63, wid = tid >> 6;
  int i = blockIdx.x * 1024 + tid;
  int v = (i < Nn) ? degi[i] : 0;
  if (i < Nn) dis[i] = rsqrtf((float)(v + 1));   // self-loop adds 1
  int incl = v;
  #pragma unroll
  for (int off = 1; off < 64; off <<= 1) {
    int t = __shfl_up(incl, off);
    if (lane >= off) incl += t;
  }
  if (lane == 63) wsum[wid] = incl;
  __syncthreads();
  if (wid == 0) {
    int wv = (lane < 16) ? wsum[lane] : 0;
    #pragma unroll
    for (int off = 1; off < 16; off <<= 1) {
      int t = __shfl_up(wv, off);
      if (lane >= off) wv += t;
    }
    if (lane < 16) wsum[lane] = wv;  // inclusive over wave totals
  }
  __syncthreads();
  int woff = (wid > 0) ? wsum[wid - 1] : 0;
  if (i < Nn) rowptr[i] = woff + incl - v;       // block-local exclusive
  if (tid == 0) bsum[blockIdx.x] = wsum[15];     // block total
}

// ---------------- scan phase 2: exclusive scan of 49 block sums ----------------
__global__ __launch_bounds__(64) void k_scan2(int* __restrict__ bsum,
                                              int* __restrict__ rowptr) {
  int lane = threadIdx.x;
  int v = (lane < SCAN_B) ? bsum[lane] : 0;
  int incl = v;
  #pragma unroll
  for (int off = 1; off < 64; off <<= 1) {
    int t = __shfl_up(incl, off);
    if (lane >= off) incl += t;
  }
  if (lane < SCAN_B) bsum[lane] = incl - v;      // exclusive block offsets
  if (lane == 63) rowptr[Nn] = incl;             // == Ne
}

// ---------------- scan phase 3: add block offsets ----------------
__global__ __launch_bounds__(1024) void k_scan3(int* __restrict__ rowptr,
                                                const int* __restrict__ bsum) {
  int i = blockIdx.x * 1024 + threadIdx.x;
  if (i < Nn) rowptr[i] += bsum[blockIdx.x];
}

// ---------------- CSR fill (incoming lists, packed {src, norm}) ----------------
__global__ __launch_bounds__(256) void k_fill(const int* __restrict__ row,
                                              const int* __restrict__ col,
                                              const float* __restrict__ dis,
                                              const int* __restrict__ rowptr,
                                              int* __restrict__ cursor,
                                              int2* __restrict__ csr) {
  int e = blockIdx.x * 256 + threadIdx.x;
  if (e >= Ne) return;
  int r = row[e], c = col[e];
  int pos = rowptr[c] + atomicAdd(&cursor[c], 1);
  csr[pos] = make_int2(r, __float_as_int(dis[r] * dis[c]));
}

// ---------------- tiled GEMM: H[n, ldo](fp16) = X[n,128] @ W[128, ldo] ----------------
// Block: 256 thr = 16 tx (4 cols each) x 16 ty (4 nodes each).
// LDS: W col-slice 128x64 (32 KB) + X tile 64x128 (32 KB) = 64 KB -> 2 blocks/CU.
__global__ __launch_bounds__(256) void k_gemm(const float* __restrict__ X,
                                              const float* __restrict__ W,
                                              __half* __restrict__ H,
                                              int n, int ldo) {
  __shared__ float Wl[128 * 64];   // [k][c] c within slice
  __shared__ float Xl[64 * 128];   // [node][k]
  const int tid = threadIdx.x;
  const int tx = tid & 15, ty = tid >> 4;
  const int base = blockIdx.x * 64;
  const int colbase = blockIdx.y * 64;

  {
    const float4* Wg = (const float4*)W;
    float4* Ws = (float4*)Wl;
    const int ldw4 = ldo >> 2, cb4 = colbase >> 2;
    #pragma unroll
    for (int i = 0; i < 8; ++i) {
      int idx = tid + i * 256;          // 0..2047
      int r = idx >> 4, c4 = idx & 15;
      Ws[idx] = Wg[r * ldw4 + cb4 + c4];
    }
  }
  {
    const float4* Xg = (const float4*)X;
    float4* Xs = (float4*)Xl;
    #pragma unroll
    for (int i = 0; i < 8; ++i) {
      int idx = tid + i * 256;          // 0..2047
      int node = base + (idx >> 5);
      int nc = node < n ? node : n - 1;
      Xs[idx] = Xg[(size_t)nc * 32 + (idx & 31)];
    }
  }
  __syncthreads();

  float a[4][4];
  #pragma unroll
  for (int m = 0; m < 4; ++m)
    #pragma unroll
    for (int c = 0; c < 4; ++c) a[m][c] = 0.f;

  #pragma unroll 4
  for (int k = 0; k < 128; k += 4) {
    float4 w0 = *(const float4*)&Wl[(k + 0) * 64 + (tx << 2)];
    float4 w1 = *(const float4*)&Wl[(k + 1) * 64 + (tx << 2)];
    float4 w2 = *(const float4*)&Wl[(k + 2) * 64 + (tx << 2)];
    float4 w3 = *(const float4*)&Wl[(k + 3) * 64 + (tx << 2)];
    #pragma unroll
    for (int m = 0; m < 4; ++m) {
      float4 xv = *(const float4*)&Xl[(ty * 4 + m) * 128 + k];
      a[m][0] = fmaf(xv.x, w0.x, a[m][0]);
      a[m][0] = fmaf(xv.y, w1.x, a[m][0]);
      a[m][0] = fmaf(xv.z, w2.x, a[m][0]);
      a[m][0] = fmaf(xv.w, w3.x, a[m][0]);
      a[m][1] = fmaf(xv.x, w0.y, a[m][1]);
      a[m][1] = fmaf(xv.y, w1.y, a[m][1]);
      a[m][1] = fmaf(xv.z, w2.y, a[m][1]);
      a[m][1] = fmaf(xv.w, w3.y, a[m][1]);
      a[m][2] = fmaf(xv.x, w0.z, a[m][2]);
      a[m][2] = fmaf(xv.y, w1.z, a[m][2]);
      a[m][2] = fmaf(xv.z, w2.z, a[m][2]);
      a[m][2] = fmaf(xv.w, w3.z, a[m][2]);
      a[m][3] = fmaf(xv.x, w0.w, a[m][3]);
      a[m][3] = fmaf(xv.y, w1.w, a[m][3]);
      a[m][3] = fmaf(xv.z, w2.w, a[m][3]);
      a[m][3] = fmaf(xv.w, w3.w, a[m][3]);
    }
  }

  #pragma unroll
  for (int m = 0; m < 4; ++m) {
    int node = base + ty * 4 + m;
    if (node < n) {
      __half2 p0 = __float22half2_rn(make_float2(a[m][0], a[m][1]));
      __half2 p1 = __float22half2_rn(make_float2(a[m][2], a[m][3]));
      uint2 st;
      st.x = *(const unsigned int*)&p0;
      st.y = *(const unsigned int*)&p1;
      *(uint2*)(H + (size_t)node * ldo + colbase + (tx << 2)) = st;
    }
  }
}

// ---------------- aggregate 128 feats (+bias, relu), fp16 gather, 8-wide ----------------
// Lane owns half2 pair index `lane` (feats 2*lane, 2*lane+1); 256 B/edge gather.
__global__ __launch_bounds__(256) void k_agg128(const __half* __restrict__ H,
                                                const int2* __restrict__ csr,
                                                const int* __restrict__ rowptr,
                                                const float* __restrict__ dis,
                                                const float* __restrict__ bias,
                                                float* __restrict__ Out, int n) {
  int wid = threadIdx.x >> 6, lane = threadIdx.x & 63;
  int v = blockIdx.x * 4 + wid;
  if (v >= n) return;
  int s = rowptr[v], e = rowptr[v + 1];
  float d = dis[v];
  float sw = d * d;                              // self-loop norm = 1/deg
  const __half2* Hp = (const __half2*)H;         // 64 pairs per row
  float2 h = __half22float2(Hp[(size_t)v * 64 + lane]);
  float a0 = h.x * sw, a1 = h.y * sw;
  int i = s;
  for (; i + 8 <= e; i += 8) {
    int2 e0 = csr[i + 0], e1 = csr[i + 1], e2 = csr[i + 2], e3 = csr[i + 3];
    int2 e4 = csr[i + 4], e5 = csr[i + 5], e6 = csr[i + 6], e7 = csr[i + 7];
    float2 h0 = __half22float2(Hp[(size_t)e0.x * 64 + lane]);
    float2 h1 = __half22float2(Hp[(size_t)e1.x * 64 + lane]);
    float2 h2 = __half22float2(Hp[(size_t)e2.x * 64 + lane]);
    float2 h3 = __half22float2(Hp[(size_t)e3.x * 64 + lane]);
    float2 h4 = __half22float2(Hp[(size_t)e4.x * 64 + lane]);
    float2 h5 = __half22float2(Hp[(size_t)e5.x * 64 + lane]);
    float2 h6 = __half22float2(Hp[(size_t)e6.x * 64 + lane]);
    float2 h7 = __half22float2(Hp[(size_t)e7.x * 64 + lane]);
    float w0 = __int_as_float(e0.y), w1 = __int_as_float(e1.y);
    float w2 = __int_as_float(e2.y), w3 = __int_as_float(e3.y);
    float w4 = __int_as_float(e4.y), w5 = __int_as_float(e5.y);
    float w6 = __int_as_float(e6.y), w7 = __int_as_float(e7.y);
    a0 = fmaf(w0, h0.x, a0); a1 = fmaf(w0, h0.y, a1);
    a0 = fmaf(w1, h1.x, a0); a1 = fmaf(w1, h1.y, a1);
    a0 = fmaf(w2, h2.x, a0); a1 = fmaf(w2, h2.y, a1);
    a0 = fmaf(w3, h3.x, a0); a1 = fmaf(w3, h3.y, a1);
    a0 = fmaf(w4, h4.x, a0); a1 = fmaf(w4, h4.y, a1);
    a0 = fmaf(w5, h5.x, a0); a1 = fmaf(w5, h5.y, a1);
    a0 = fmaf(w6, h6.x, a0); a1 = fmaf(w6, h6.y, a1);
    a0 = fmaf(w7, h7.x, a0); a1 = fmaf(w7, h7.y, a1);
  }
  for (; i < e; ++i) {
    int2 ee = csr[i];
    float2 hs = __half22float2(Hp[(size_t)ee.x * 64 + lane]);
    float w = __int_as_float(ee.y);
    a0 = fmaf(w, hs.x, a0);
    a1 = fmaf(w, hs.y, a1);
  }
  float2 b = *(const float2*)(bias + 2 * lane);
  a0 = fmaxf(a0 + b.x, 0.f);
  a1 = fmaxf(a1 + b.y, 0.f);
  *(float2*)(Out + (size_t)v * 128 + 2 * lane) = make_float2(a0, a1);
}

// ---------------- aggregate 64 feats (+bias), fp16 gather, 2 nodes/wave ----------------
// Half-wave per node: lanes 0-31 -> node v0, lanes 32-63 -> node v1.
// Each lane owns half2 pair (lane&31); 128 B/row, 2 rows per gather instr.
__global__ __launch_bounds__(256) void k_agg64(const __half* __restrict__ H,
                                               const int2* __restrict__ csr,
                                               const int* __restrict__ rowptr,
                                               const float* __restrict__ dis,
                                               const float* __restrict__ bias,
                                               float* __restrict__ Out, int n) {
  int wid = threadIdx.x >> 6, lane = threadIdx.x & 63;
  int fl = lane & 31;                            // feat-pair index
  int v = blockIdx.x * 8 + wid * 2 + (lane >> 5);
  if (v >= n) return;
  int s = rowptr[v], e = rowptr[v + 1];
  float d = dis[v];
  const __half2* Hp = (const __half2*)H;         // 32 pairs per row
  float2 hv = __half22float2(Hp[(size_t)v * 32 + fl]);
  float sw = d * d;
  float a0 = hv.x * sw, a1 = hv.y * sw;
  int i = s;
  for (; i + 8 <= e; i += 8) {
    int2 e0 = csr[i + 0], e1 = csr[i + 1], e2 = csr[i + 2], e3 = csr[i + 3];
    int2 e4 = csr[i + 4], e5 = csr[i + 5], e6 = csr[i + 6], e7 = csr[i + 7];
    float2 h0 = __half22float2(Hp[(size_t)e0.x * 32 + fl]);
    float2 h1 = __half22float2(Hp[(size_t)e1.x * 32 + fl]);
    float2 h2 = __half22float2(Hp[(size_t)e2.x * 32 + fl]);
    float2 h3 = __half22float2(Hp[(size_t)e3.x * 32 + fl]);
    float2 h4 = __half22float2(Hp[(size_t)e4.x * 32 + fl]);
    float2 h5 = __half22float2(Hp[(size_t)e5.x * 32 + fl]);
    float2 h6 = __half22float2(Hp[(size_t)e6.x * 32 + fl]);
    float2 h7 = __half22float2(Hp[(size_t)e7.x * 32 + fl]);
    float w0 = __int_as_float(e0.y), w1 = __int_as_float(e1.y);
    float w2 = __int_as_float(e2.y), w3 = __int_as_float(e3.y);
    float w4 = __int_as_float(e4.y), w5 = __int_as_float(e5.y);
    float w6 = __int_as_float(e6.y), w7 = __int_as_float(e7.y);
    a0 = fmaf(w0, h0.x, a0); a1 = fmaf(w0, h0.y, a1);
    a0 = fmaf(w1, h1.x, a0); a1 = fmaf(w1, h1.y, a1);
    a0 = fmaf(w2, h2.x, a0); a1 = fmaf(w2, h2.y, a1);
    a0 = fmaf(w3, h3.x, a0); a1 = fmaf(w3, h3.y, a1);
    a0 = fmaf(w4, h4.x, a0); a1 = fmaf(w4, h4.y, a1);
    a0 = fmaf(w5, h5.x, a0); a1 = fmaf(w5, h5.y, a1);
    a0 = fmaf(w6, h6.x, a0); a1 = fmaf(w6, h6.y, a1);
    a0 = fmaf(w7, h7.x, a0); a1 = fmaf(w7, h7.y, a1);
  }
  for (; i < e; ++i) {
    int2 ee = csr[i];
    float2 hs = __half22float2(Hp[(size_t)ee.x * 32 + fl]);
    float w = __int_as_float(ee.y);
    a0 = fmaf(w, hs.x, a0);
    a1 = fmaf(w, hs.y, a1);
  }
  float2 b = *(const float2*)(bias + 2 * fl);
  *(float2*)(Out + (size_t)v * 64 + 2 * fl) = make_float2(a0 + b.x, a1 + b.y);
}

extern "C" void kernel_launch(void* const* d_in, const int* in_sizes, int n_in,
                              void* d_out, int out_size, void* d_ws, size_t ws_size,
                              hipStream_t stream) {
  const float* x  = (const float*)d_in[0];
  const int*   ei = (const int*)d_in[1];    // [2, E] row-major
  const int*   row = ei;                    // edge_index[0] (source)
  const int*   col = ei + Ne;               // edge_index[1] (dest / segment)
  const float* W1 = (const float*)d_in[2];
  const float* b1 = (const float*)d_in[3];
  const float* W2 = (const float*)d_in[4];
  const float* b2 = (const float*)d_in[5];
  float* out = (float*)d_out;

  char* ws = (char*)d_ws;
  size_t off = 0;
  auto alloc = [&](size_t bytes) -> void* {
    void* p = ws + off;
    off += (bytes + 255) & ~(size_t)255;
    return p;
  };
  int*    degi   = (int*)   alloc(Nn * sizeof(int));
  int*    cursor = (int*)   alloc(Nn * sizeof(int));
  int*    rowptr = (int*)   alloc((Nn + 1) * sizeof(int));
  float*  dis    = (float*) alloc(Nn * sizeof(float));
  int*    bsum   = (int*)   alloc(64 * sizeof(int));
  int2*   csr    = (int2*)  alloc((size_t)Ne * sizeof(int2));
  __half* H1     = (__half*)alloc((size_t)Nn * 128 * sizeof(__half));  // 12.8 MB
  float*  H1b    = (float*) alloc((size_t)Nn * 128 * sizeof(float));   // 25.6 MB
  __half* H2     = (__half*)alloc((size_t)Nn * 64 * sizeof(__half));   // 6.4 MB

  hipMemsetAsync(degi, 0, Nn * sizeof(int), stream);
  hipMemsetAsync(cursor, 0, Nn * sizeof(int), stream);

  const int EB  = (Ne + 255) / 256;         // 3125
  const int NB4 = (Nn + 3) / 4;             // 12500 (wave per node, agg128)
  const int NB8 = (Nn + 7) / 8;             // 6250  (2 nodes per wave, agg64)
  const int GT  = (Nn + 63) / 64;           // 782 node tiles (gemm)

  k_count<<<EB, 256, 0, stream>>>(col, degi);
  k_scan1<<<SCAN_B, 1024, 0, stream>>>(degi, rowptr, dis, bsum);
  k_scan2<<<1, 64, 0, stream>>>(bsum, rowptr);
  k_scan3<<<SCAN_B, 1024, 0, stream>>>(rowptr, bsum);
  k_fill<<<EB, 256, 0, stream>>>(row, col, dis, rowptr, cursor, csr);

  // layer 1: H1 = fp16(x @ W1) ; H1b = relu(agg(H1) + b1)
  k_gemm<<<dim3(GT, 2), 256, 0, stream>>>(x, W1, H1, Nn, 128);
  k_agg128<<<NB4, 256, 0, stream>>>(H1, csr, rowptr, dis, b1, H1b, Nn);

  // layer 2: H2 = fp16(H1b @ W2) ; out = agg(H2) + b2
  k_gemm<<<dim3(GT, 1), 256, 0, stream>>>(H1b, W2, H2, Nn, 64);
  k_agg64<<<NB8, 256, 0, stream>>>(H2, csr, rowptr, dis, b2, out, Nn);
}